// Round 4
// baseline (112.877 us; speedup 1.0000x reference)
//
#include <hip/hip_runtime.h>
#include <cstdint>
#include <cmath>

#define B_ 2
#define L_ 1024
#define D_ 256
#define U_ 32
#define ROWS_ 2048   // B_*L_
#define WBS 280      // LDS wb row stride (halfwords): 560B, 16B-aligned
#define PSTR 1032    // LDS P row stride (halfwords): 2064B, 16B-aligned

typedef __attribute__((ext_vector_type(8))) short short8;
typedef __attribute__((ext_vector_type(4))) float floatx4;

// ---- workspace layout (bytes) ------------------------------------------------
// P holds EXP2 of the scaled logits: rows 0-31: equ = exp2(SC*(q·Wt+bh));
// rows 32-63: ekk = exp2(SC*(k·Wx)).  exp2(qu+kk) == equ*ekk (hoisted).
#define OFF_P  0u                      // [64][2048] f32 = 512 KB
#define OFF_XT (OFF_P + 524288u)       // [B][D][L] bf16 = 1 MB
#define OFF_WV (OFF_XT + 1048576u)     // [32] f32 = 128 B  (-2*Wa)

__device__ __forceinline__ float bf2f(unsigned short u) {
    union { unsigned int i; float f; } v; v.i = ((unsigned int)u) << 16; return v.f;
}
__device__ __forceinline__ unsigned short f2bf(float f) {
    union { float f; unsigned int i; } v; v.f = f;
    unsigned int r = v.i + 0x7FFFu + ((v.i >> 16) & 1u);
    return (unsigned short)(r >> 16);
}
__device__ __forceinline__ unsigned int pack_bf(float a, float b) {
    union { float f; unsigned int i; } ua, ub; ua.f = a; ub.f = b;
    unsigned int ra = ua.i + 0x7FFFu + ((ua.i >> 16) & 1u);
    unsigned int rb = ub.i + 0x7FFFu + ((ub.i >> 16) & 1u);
    return (ra >> 16) | (rb & 0xFFFF0000u);
}

// Inline dtype sniff (per wave). Returns 1 = fp32, 0 = bf16.
__device__ __forceinline__ int sniff_is_f32(const void* x) {
    const unsigned short* xu = (const unsigned short*)x;
    float f = bf2f(xu[2 * (threadIdx.x & 63)]);
    bool plausible = (f == f) && (fabsf(f) < 1e4f) && (fabsf(f) > 1e-10f);
    unsigned long long m = __ballot(plausible);
    return (__popcll(m) >= 60) ? 0 : 1;
}

// convert 8 consecutive f32 -> short8 bf16 (RNE)
__device__ __forceinline__ short8 cvt8(const float* p) {
    float4 fa = *(const float4*)p;
    float4 fb = *(const float4*)(p + 4);
    union { short8 s; unsigned int u[4]; } r;
    r.u[0] = pack_bf(fa.x, fa.y);
    r.u[1] = pack_bf(fa.z, fa.w);
    r.u[2] = pack_bf(fb.x, fb.y);
    r.u[3] = pack_bf(fb.z, fb.w);
    return r.s;
}

// ---------------------------------------------------------------------------
// K1 proj_all (R2-EXACT, proven 3x): per block (64 blocks x 256 thr = 4
// waves), rows n0..n0+31:
//   1. stage Wt^T and Wx into LDS wb[64][WBS] bf16 (A-operand layout).
//   2. wave (mt, rh) computes logits via MFMA 16x16x32; B-frags = x rows
//      (read once). mt=0 waves deposit B-frags into xtile.
//   3. P stores EXP2 of the scaled logits.
//   4. coalesced uint stores of xtile -> xT[b][d][l].
// Block 0 also precomputes WV[u] = -2*Wa[u] (f32).
// [R3 post-mortem: the R3 double-change (K1 512-thr k-split + K2 key-split)
//  crashed; this round isolates by reverting K1 to the proven version.]
// ---------------------------------------------------------------------------
__global__ void proj_all(const void* __restrict__ x,  const void* __restrict__ Wt,
                         const void* __restrict__ Wx, const void* __restrict__ bh,
                         const void* __restrict__ Wa,
                         float* __restrict__ P, unsigned short* __restrict__ xT,
                         float* __restrict__ WV) {
    const int t = threadIdx.x;
    const int isf32 = sniff_is_f32(x);
    const int n0 = blockIdx.x * 32;
    const int b  = n0 >> 10;
    const int l0 = n0 & (L_ - 1);
    __shared__ unsigned short wb[64 * WBS];      // 35.0 KB
    __shared__ unsigned short xtile[D_ * 34];    // 17.0 KB

    if (blockIdx.x == 0 && t < U_) {
        float wav = isf32 ? ((const float*)Wa)[t] : bf2f(((const unsigned short*)Wa)[t]);
        WV[t] = -2.0f * wav;
    }

    for (int j = 0; j < 32; ++j) {
        const int i = t + 256 * j;               // i = d*32 + u
        unsigned short v = isf32 ? f2bf(((const float*)Wt)[i])
                                 : ((const unsigned short*)Wt)[i];
        wb[(i & 31) * WBS + (i >> 5)] = v;
    }
    for (int j = 0; j < 32; ++j) {
        const int e = t + 256 * j;               // e = u*256 + d
        unsigned short v = isf32 ? f2bf(((const float*)Wx)[e])
                                 : ((const unsigned short*)Wx)[e];
        wb[(32 + (e >> 8)) * WBS + (e & 255)] = v;
    }
    __syncthreads();

    const int w    = t >> 6;
    const int lane = t & 63;
    const int mt   = w & 1;         // 0 -> units 0-31 (q), 1 -> units 32-63 (k)
    const int rh   = w >> 1;
    const int m    = lane & 15;
    const int kho  = lane >> 4;
    const int u0   = mt * 32;
    const int row  = n0 + 16 * rh + m;

    floatx4 acc0 = {0,0,0,0}, acc1 = {0,0,0,0};
    #pragma unroll
    for (int k0 = 0; k0 < D_; k0 += 32) {
        const int ks = k0 + kho * 8;
        short8 a0 = *(const short8*)(wb + (u0 + m) * WBS + ks);
        short8 a1 = *(const short8*)(wb + (u0 + 16 + m) * WBS + ks);
        short8 b0;
        if (isf32) b0 = cvt8((const float*)x + (size_t)row * D_ + ks);
        else       b0 = *(const short8*)((const unsigned short*)x + (size_t)row * D_ + ks);
        acc0 = __builtin_amdgcn_mfma_f32_16x16x32_bf16(a0, b0, acc0, 0, 0, 0);
        acc1 = __builtin_amdgcn_mfma_f32_16x16x32_bf16(a1, b0, acc1, 0, 0, 0);
        if (mt == 0) {
            union { short8 s; unsigned short h[8]; } uu; uu.s = b0;
            #pragma unroll
            for (int jj = 0; jj < 8; ++jj)
                xtile[(ks + jj) * 34 + 16 * rh + m] = uu.h[jj];
        }
    }

    const float SC = 2.0f * 1.4426950408889634f;   // 2*log2(e)
    const int col = lane & 15;
    const int rb  = (lane >> 4) * 4;
    #pragma unroll
    for (int r = 0; r < 4; ++r) {
        const int ua = u0 + rb + r, ub_ = u0 + 16 + rb + r;
        float bh0 = 0.f, bh1 = 0.f;
        if (mt == 0) {
            bh0 = isf32 ? ((const float*)bh)[rb + r]      : bf2f(((const unsigned short*)bh)[rb + r]);
            bh1 = isf32 ? ((const float*)bh)[16 + rb + r] : bf2f(((const unsigned short*)bh)[16 + rb + r]);
        }
        P[(size_t)ua  * ROWS_ + n0 + 16 * rh + col] = __builtin_amdgcn_exp2f(SC * (acc0[r] + bh0));
        P[(size_t)ub_ * ROWS_ + n0 + 16 * rh + col] = __builtin_amdgcn_exp2f(SC * (acc1[r] + bh1));
    }

    __syncthreads();
    unsigned short* xtb = xT + (size_t)b * (D_ * L_) + l0;
    #pragma unroll
    for (int i = 0; i < 16; ++i) {
        const int idx = t + 256 * i;             // idx = d*16 + wq
        const int d = idx >> 4, wq = idx & 15;
        unsigned int p = *(const unsigned int*)(xtile + d * 34 + 2 * wq);
        *(unsigned int*)(xtb + (size_t)d * L_ + 2 * wq) = p;
    }
}

// ---------------------------------------------------------------------------
// K2 alpha_pv (R4): FUSED alpha+softmax+PV. 256 blocks x 512 thr (8 waves).
// Phase 1: R1-proven form (direct L2 float4 reads of ekk, shfl-broadcast
//   equ/wu).  alpha_eff[key] = sum_u wu * rcp(equ*ekk + 1).
// Wave softmax; normalized bf16 row -> LDS Pl[w][*] (8 rows, R2-proven).
// Phase 2 (ONLY unproven change this round -- key-split): wave (ds, kh):
//   d-slice [64ds, 64ds+64) over key half [512kh, 512kh+512) -- 16-iter
//   dependent-load chain (was 32), 4 d-streams; kh=1 partials -> LDS,
//   kh=0 reduces + stores.  [Theory: grid = 1 block/CU -> 2 waves/SIMD,
//   phase-2 prefetch-depth-1 chain latency-exposed; split doubles
//   in-flight loads per chain step.]
// LDS: Pl 16.5 KB + accb 16 KB = 32.5 KB.
// ---------------------------------------------------------------------------
__global__ __launch_bounds__(512) void alpha_pv(const float* __restrict__ P,
                                                const float* __restrict__ WV,
                                                const void* __restrict__ x,
                                                const unsigned short* __restrict__ xT,
                                                void* __restrict__ out) {
    const int t    = threadIdx.x;
    const int w    = t >> 6;                 // 0..7
    const int lane = t & 63;
    const int row  = blockIdx.x * 8 + w;     // global row = b*L + qi
    const int b    = row >> 10;
    const int isf32 = sniff_is_f32(x);
    __shared__ unsigned short Pl[8 * PSTR];    // 16.5 KB
    __shared__ float accb[16 * 256];           // 16 KB PV partial-acc reduce

    // ---- phase 1: alpha + softmax (u-outer; lane holds keys jj*256+4*lane+c)
    const float* Pq = P + row;                              // equ: stride ROWS_ per u
    const float* kb = P + (size_t)32 * ROWS_ + (size_t)b * L_ + 4 * lane;

    float eq_l = 0.f, wu_l = 0.f;
    if (lane < U_) {
        eq_l = Pq[(size_t)lane * ROWS_];
        wu_l = WV[lane];
    }

    float alp[16];
    #pragma unroll
    for (int j = 0; j < 16; ++j) alp[j] = 0.f;

    #pragma unroll 4
    for (int u = 0; u < U_; ++u) {
        const float equ = __shfl(eq_l, u, 64);
        const float wu  = __shfl(wu_l, u, 64);
        const float* kr = kb + (size_t)u * ROWS_;
        float4 k0 = *(const float4*)(kr);
        float4 k1 = *(const float4*)(kr + 256);
        float4 k2 = *(const float4*)(kr + 512);
        float4 k3 = *(const float4*)(kr + 768);
        alp[0]  = fmaf(wu, __builtin_amdgcn_rcpf(fmaf(equ, k0.x, 1.f)), alp[0]);
        alp[1]  = fmaf(wu, __builtin_amdgcn_rcpf(fmaf(equ, k0.y, 1.f)), alp[1]);
        alp[2]  = fmaf(wu, __builtin_amdgcn_rcpf(fmaf(equ, k0.z, 1.f)), alp[2]);
        alp[3]  = fmaf(wu, __builtin_amdgcn_rcpf(fmaf(equ, k0.w, 1.f)), alp[3]);
        alp[4]  = fmaf(wu, __builtin_amdgcn_rcpf(fmaf(equ, k1.x, 1.f)), alp[4]);
        alp[5]  = fmaf(wu, __builtin_amdgcn_rcpf(fmaf(equ, k1.y, 1.f)), alp[5]);
        alp[6]  = fmaf(wu, __builtin_amdgcn_rcpf(fmaf(equ, k1.z, 1.f)), alp[6]);
        alp[7]  = fmaf(wu, __builtin_amdgcn_rcpf(fmaf(equ, k1.w, 1.f)), alp[7]);
        alp[8]  = fmaf(wu, __builtin_amdgcn_rcpf(fmaf(equ, k2.x, 1.f)), alp[8]);
        alp[9]  = fmaf(wu, __builtin_amdgcn_rcpf(fmaf(equ, k2.y, 1.f)), alp[9]);
        alp[10] = fmaf(wu, __builtin_amdgcn_rcpf(fmaf(equ, k2.z, 1.f)), alp[10]);
        alp[11] = fmaf(wu, __builtin_amdgcn_rcpf(fmaf(equ, k2.w, 1.f)), alp[11]);
        alp[12] = fmaf(wu, __builtin_amdgcn_rcpf(fmaf(equ, k3.x, 1.f)), alp[12]);
        alp[13] = fmaf(wu, __builtin_amdgcn_rcpf(fmaf(equ, k3.y, 1.f)), alp[13]);
        alp[14] = fmaf(wu, __builtin_amdgcn_rcpf(fmaf(equ, k3.z, 1.f)), alp[14]);
        alp[15] = fmaf(wu, __builtin_amdgcn_rcpf(fmaf(equ, k3.w, 1.f)), alp[15]);
    }

    float amax = alp[0];
    #pragma unroll
    for (int j = 1; j < 16; ++j) amax = fmaxf(amax, alp[j]);
    #pragma unroll
    for (int off = 32; off > 0; off >>= 1) amax = fmaxf(amax, __shfl_xor(amax, off, 64));

    const float L2E = 1.4426950408889634f;
    float s = 0.f;
    #pragma unroll
    for (int j = 0; j < 16; ++j) {
        alp[j] = __builtin_amdgcn_exp2f((alp[j] - amax) * L2E);
        s += alp[j];
    }
    #pragma unroll
    for (int off = 32; off > 0; off >>= 1) s += __shfl_xor(s, off, 64);
    const float rinv = __builtin_amdgcn_rcpf(s);

    #pragma unroll
    for (int jj = 0; jj < 4; ++jj) {
        ushort4 pk;
        pk.x = f2bf(alp[4*jj+0] * rinv);
        pk.y = f2bf(alp[4*jj+1] * rinv);
        pk.z = f2bf(alp[4*jj+2] * rinv);
        pk.w = f2bf(alp[4*jj+3] * rinv);
        *(ushort4*)(Pl + w * PSTR + jj * 256 + 4 * lane) = pk;   // key = jj*256+4*lane+c
    }
    __syncthreads();

    // ---- phase 2: PV, key-split.  wave (ds,kh): d [64ds,64ds+64) x keys [512kh,+512)
    const int ds = w & 3;
    const int kh = w >> 2;
    const int m  = lane & 15;
    const int ko = (lane >> 4) * 8 + kh * 512;
    const int d0 = ds * 64;
    const unsigned short* xbb = xT + (size_t)b * (D_ * L_) + (size_t)(d0 + m) * L_ + ko;
    const unsigned short* xb0 = xbb;
    const unsigned short* xb1 = xbb + (size_t)16 * L_;
    const unsigned short* xb2 = xbb + (size_t)32 * L_;
    const unsigned short* xb3 = xbb + (size_t)48 * L_;
    const unsigned short* pp  = Pl + (size_t)(m & 7) * PSTR + ko;  // A rows 8-15 alias 0-7

    floatx4 acc0 = {0,0,0,0}, acc1 = {0,0,0,0}, acc2 = {0,0,0,0}, acc3 = {0,0,0,0};
    short8 pa = *(const short8*)(pp);
    short8 x0 = *(const short8*)(xb0);
    short8 x1 = *(const short8*)(xb1);
    short8 x2 = *(const short8*)(xb2);
    short8 x3 = *(const short8*)(xb3);
    for (int ks = 32; ks < 512; ks += 32) {
        short8 npa = *(const short8*)(pp + ks);
        short8 nx0 = *(const short8*)(xb0 + ks);
        short8 nx1 = *(const short8*)(xb1 + ks);
        short8 nx2 = *(const short8*)(xb2 + ks);
        short8 nx3 = *(const short8*)(xb3 + ks);
        acc0 = __builtin_amdgcn_mfma_f32_16x16x32_bf16(pa, x0, acc0, 0, 0, 0);
        acc1 = __builtin_amdgcn_mfma_f32_16x16x32_bf16(pa, x1, acc1, 0, 0, 0);
        acc2 = __builtin_amdgcn_mfma_f32_16x16x32_bf16(pa, x2, acc2, 0, 0, 0);
        acc3 = __builtin_amdgcn_mfma_f32_16x16x32_bf16(pa, x3, acc3, 0, 0, 0);
        pa = npa; x0 = nx0; x1 = nx1; x2 = nx2; x3 = nx3;
    }
    acc0 = __builtin_amdgcn_mfma_f32_16x16x32_bf16(pa, x0, acc0, 0, 0, 0);
    acc1 = __builtin_amdgcn_mfma_f32_16x16x32_bf16(pa, x1, acc1, 0, 0, 0);
    acc2 = __builtin_amdgcn_mfma_f32_16x16x32_bf16(pa, x2, acc2, 0, 0, 0);
    acc3 = __builtin_amdgcn_mfma_f32_16x16x32_bf16(pa, x3, acc3, 0, 0, 0);

    // kh=1 deposits partials; kh=0 reduces and stores
    if (kh == 1) {
        *(floatx4*)(&accb[(ds * 4 + 0) * 256 + lane * 4]) = acc0;
        *(floatx4*)(&accb[(ds * 4 + 1) * 256 + lane * 4]) = acc1;
        *(floatx4*)(&accb[(ds * 4 + 2) * 256 + lane * 4]) = acc2;
        *(floatx4*)(&accb[(ds * 4 + 3) * 256 + lane * 4]) = acc3;
    }
    __syncthreads();

    if (kh == 0) {
        acc0 += *(const floatx4*)(&accb[(ds * 4 + 0) * 256 + lane * 4]);
        acc1 += *(const floatx4*)(&accb[(ds * 4 + 1) * 256 + lane * 4]);
        acc2 += *(const floatx4*)(&accb[(ds * 4 + 2) * 256 + lane * 4]);
        acc3 += *(const floatx4*)(&accb[(ds * 4 + 3) * 256 + lane * 4]);

        // C/D layout: col = lane&15 (= d offset), row = (lane>>4)*4 + reg (= q)
        const int col = lane & 15;
        const int rb  = (lane >> 4) * 4;
        const int qi0 = (blockIdx.x * 8) & (L_ - 1);   // LOCAL q index
        const size_t obase = (size_t)b * (L_ * D_) + (size_t)qi0 * D_;
        if (rb < 8) {   // lanes 0-31 hold valid q-rows 0-7
            if (isf32) {
                float* ob = (float*)out + obase;
                #pragma unroll
                for (int r = 0; r < 4; ++r) {
                    ob[(size_t)(rb + r) * D_ + d0 + col]      = acc0[r];
                    ob[(size_t)(rb + r) * D_ + d0 + 16 + col] = acc1[r];
                    ob[(size_t)(rb + r) * D_ + d0 + 32 + col] = acc2[r];
                    ob[(size_t)(rb + r) * D_ + d0 + 48 + col] = acc3[r];
                }
            } else {
                unsigned short* ob = (unsigned short*)out + obase;
                #pragma unroll
                for (int r = 0; r < 4; ++r) {
                    ob[(size_t)(rb + r) * D_ + d0 + col]      = f2bf(acc0[r]);
                    ob[(size_t)(rb + r) * D_ + d0 + 16 + col] = f2bf(acc1[r]);
                    ob[(size_t)(rb + r) * D_ + d0 + 32 + col] = f2bf(acc2[r]);
                    ob[(size_t)(rb + r) * D_ + d0 + 48 + col] = f2bf(acc3[r]);
                }
            }
        }
    }
}

extern "C" void kernel_launch(void* const* d_in, const int* in_sizes, int n_in,
                              void* d_out, int out_size, void* d_ws, size_t ws_size,
                              hipStream_t stream) {
    const void* x  = d_in[0];   // [B,L,D]  dtype sniffed at runtime (fp32 expected)
    const void* Wt = d_in[1];   // [D,U]
    const void* Wx = d_in[2];   // [U,D]
    const void* bh = d_in[3];   // [U]
    const void* Wa = d_in[4];   // [U,1]
    // d_in[5] = ba: constant pre-softmax shift -> mathematically irrelevant.

    char* ws = (char*)d_ws;
    float*          P   = (float*)(ws + OFF_P);
    unsigned short* xT  = (unsigned short*)(ws + OFF_XT);
    float*          WV  = (float*)(ws + OFF_WV);

    proj_all<<<ROWS_ / 32, 256, 0, stream>>>(x, Wt, Wx, bh, Wa, P, xT, WV);
    alpha_pv<<<ROWS_ / 8, 512, 0, stream>>>(P, WV, x, xT, d_out);
}

// Round 5
// 101.007 us; speedup vs baseline: 1.1175x; 1.1175x over previous
//
#include <hip/hip_runtime.h>
#include <cstdint>
#include <cmath>

#define B_ 2
#define L_ 1024
#define D_ 256
#define U_ 32
#define ROWS_ 2048   // B_*L_
#define WBS 280      // LDS wb row stride (halfwords): 560B, 16B-aligned
#define PSTR 1032    // LDS P row stride (halfwords): 2064B, 16B-aligned

typedef __attribute__((ext_vector_type(8))) short short8;
typedef __attribute__((ext_vector_type(4))) float floatx4;

// ---- workspace layout (bytes) ------------------------------------------------
// P holds EXP2 of the scaled logits: rows 0-31: equ = exp2(SC*(q·Wt+bh));
// rows 32-63: ekk = exp2(SC*(k·Wx)).  exp2(qu+kk) == equ*ekk (hoisted).
#define OFF_P  0u                      // [64][2048] f32 = 512 KB
#define OFF_XT (OFF_P + 524288u)       // [B][D][L] bf16 = 1 MB
#define OFF_WV (OFF_XT + 1048576u)     // [32] f32 = 128 B  (-2*Wa)

// TIME MODEL (R4 post-mortem, consistent across R0-R4):
//   dur_us ~= 2 x 41 us poison-fills (harness reset, fixed tax)
//           + proj_all ~23 us + alpha_pv ~7.5 us.
//   All R0/R2/R4 alpha variants neutral -> alpha is at its ~7.5 us floor.
//   proj's 23 us >> 4 us model: the two ROLLED staging loops (64 serial
//   scalar global loads/thread at 1 wave/SIMD) dominate. R5 = fix only that.

__device__ __forceinline__ float bf2f(unsigned short u) {
    union { unsigned int i; float f; } v; v.i = ((unsigned int)u) << 16; return v.f;
}
__device__ __forceinline__ unsigned short f2bf(float f) {
    union { float f; unsigned int i; } v; v.f = f;
    unsigned int r = v.i + 0x7FFFu + ((v.i >> 16) & 1u);
    return (unsigned short)(r >> 16);
}
__device__ __forceinline__ unsigned int pack_bf(float a, float b) {
    union { float f; unsigned int i; } ua, ub; ua.f = a; ub.f = b;
    unsigned int ra = ua.i + 0x7FFFu + ((ua.i >> 16) & 1u);
    unsigned int rb = ub.i + 0x7FFFu + ((ub.i >> 16) & 1u);
    return (ra >> 16) | (rb & 0xFFFF0000u);
}

// Inline dtype sniff (per wave). Returns 1 = fp32, 0 = bf16.
__device__ __forceinline__ int sniff_is_f32(const void* x) {
    const unsigned short* xu = (const unsigned short*)x;
    float f = bf2f(xu[2 * (threadIdx.x & 63)]);
    bool plausible = (f == f) && (fabsf(f) < 1e4f) && (fabsf(f) > 1e-10f);
    unsigned long long m = __ballot(plausible);
    return (__popcll(m) >= 60) ? 0 : 1;
}

// convert 8 consecutive f32 -> short8 bf16 (RNE)
__device__ __forceinline__ short8 cvt8(const float* p) {
    float4 fa = *(const float4*)p;
    float4 fb = *(const float4*)(p + 4);
    union { short8 s; unsigned int u[4]; } r;
    r.u[0] = pack_bf(fa.x, fa.y);
    r.u[1] = pack_bf(fa.z, fa.w);
    r.u[2] = pack_bf(fb.x, fb.y);
    r.u[3] = pack_bf(fb.z, fb.w);
    return r.s;
}

// ---------------------------------------------------------------------------
// K1 proj_all (R5 = R0-exact EXCEPT staging loops unrolled+vectorized):
// per block (64 blocks x 256 thr = 4 waves), rows n0..n0+31:
//   1. stage Wt^T and Wx into LDS wb[64][WBS] bf16 -- NOW 16 independent
//      float4/ushort4 loads per thread (was 64 ROLLED serial scalar loads:
//      ~13 us of exposed latency at 1 wave/SIMD -- the R4 post-mortem's
//      dominant cost).
//   2. wave (mt, rh) computes logits via MFMA 16x16x32; B-frags = x rows
//      (read once). mt=0 waves deposit B-frags into xtile.
//   3. P stores EXP2 of the scaled logits.
//   4. coalesced uint stores of xtile -> xT[b][d][l].
// Block 0 also precomputes WV[u] = -2*Wa[u] (f32).
// ---------------------------------------------------------------------------
__global__ void proj_all(const void* __restrict__ x,  const void* __restrict__ Wt,
                         const void* __restrict__ Wx, const void* __restrict__ bh,
                         const void* __restrict__ Wa,
                         float* __restrict__ P, unsigned short* __restrict__ xT,
                         float* __restrict__ WV) {
    const int t = threadIdx.x;
    const int isf32 = sniff_is_f32(x);
    const int n0 = blockIdx.x * 32;
    const int b  = n0 >> 10;
    const int l0 = n0 & (L_ - 1);
    __shared__ unsigned short wb[64 * WBS];      // 35.0 KB
    __shared__ unsigned short xtile[D_ * 34];    // 17.0 KB

    if (blockIdx.x == 0 && t < U_) {
        float wav = isf32 ? ((const float*)Wa)[t] : bf2f(((const unsigned short*)Wa)[t]);
        WV[t] = -2.0f * wav;
    }

    // Wt staging: element i = 4*(t+256j), j<8.  i 4-aligned -> u = i&31 <= 28,
    // so elements i..i+3 are u..u+3 at the SAME d (no 32-boundary crossing).
    // Same wb mapping as R0: wb[u*WBS + d] = Wt[i].
    #pragma unroll
    for (int j = 0; j < 8; ++j) {
        const int i = 4 * (t + 256 * j);
        unsigned short h0, h1, h2, h3;
        if (isf32) {
            float4 v = *(const float4*)((const float*)Wt + i);
            h0 = f2bf(v.x); h1 = f2bf(v.y); h2 = f2bf(v.z); h3 = f2bf(v.w);
        } else {
            ushort4 v = *(const ushort4*)((const unsigned short*)Wt + i);
            h0 = v.x; h1 = v.y; h2 = v.z; h3 = v.w;
        }
        const int d = i >> 5, u = i & 31;
        wb[(u + 0) * WBS + d] = h0;
        wb[(u + 1) * WBS + d] = h1;
        wb[(u + 2) * WBS + d] = h2;
        wb[(u + 3) * WBS + d] = h3;
    }
    // Wx staging: e = 4*(t+256j): elements e..e+3 share row 32+(e>>8), cols
    // (e&255)..+3 contiguous -> one ushort4 LDS write (8B-aligned: row base
    // 560B % 8 == 0, col 4-aligned halfwords).  Same mapping as R0.
    #pragma unroll
    for (int j = 0; j < 8; ++j) {
        const int e = 4 * (t + 256 * j);
        ushort4 o;
        if (isf32) {
            float4 v = *(const float4*)((const float*)Wx + e);
            o.x = f2bf(v.x); o.y = f2bf(v.y); o.z = f2bf(v.z); o.w = f2bf(v.w);
        } else {
            o = *(const ushort4*)((const unsigned short*)Wx + e);
        }
        *(ushort4*)(wb + (32 + (e >> 8)) * WBS + (e & 255)) = o;
    }
    __syncthreads();

    const int w    = t >> 6;
    const int lane = t & 63;
    const int mt   = w & 1;         // 0 -> units 0-31 (q), 1 -> units 32-63 (k)
    const int rh   = w >> 1;
    const int m    = lane & 15;
    const int kho  = lane >> 4;
    const int u0   = mt * 32;
    const int row  = n0 + 16 * rh + m;

    floatx4 acc0 = {0,0,0,0}, acc1 = {0,0,0,0};
    #pragma unroll
    for (int k0 = 0; k0 < D_; k0 += 32) {
        const int ks = k0 + kho * 8;
        short8 a0 = *(const short8*)(wb + (u0 + m) * WBS + ks);
        short8 a1 = *(const short8*)(wb + (u0 + 16 + m) * WBS + ks);
        short8 b0;
        if (isf32) b0 = cvt8((const float*)x + (size_t)row * D_ + ks);
        else       b0 = *(const short8*)((const unsigned short*)x + (size_t)row * D_ + ks);
        acc0 = __builtin_amdgcn_mfma_f32_16x16x32_bf16(a0, b0, acc0, 0, 0, 0);
        acc1 = __builtin_amdgcn_mfma_f32_16x16x32_bf16(a1, b0, acc1, 0, 0, 0);
        if (mt == 0) {
            union { short8 s; unsigned short h[8]; } uu; uu.s = b0;
            #pragma unroll
            for (int jj = 0; jj < 8; ++jj)
                xtile[(ks + jj) * 34 + 16 * rh + m] = uu.h[jj];
        }
    }

    const float SC = 2.0f * 1.4426950408889634f;   // 2*log2(e)
    const int col = lane & 15;
    const int rb  = (lane >> 4) * 4;
    #pragma unroll
    for (int r = 0; r < 4; ++r) {
        const int ua = u0 + rb + r, ub_ = u0 + 16 + rb + r;
        float bh0 = 0.f, bh1 = 0.f;
        if (mt == 0) {
            bh0 = isf32 ? ((const float*)bh)[rb + r]      : bf2f(((const unsigned short*)bh)[rb + r]);
            bh1 = isf32 ? ((const float*)bh)[16 + rb + r] : bf2f(((const unsigned short*)bh)[16 + rb + r]);
        }
        P[(size_t)ua  * ROWS_ + n0 + 16 * rh + col] = __builtin_amdgcn_exp2f(SC * (acc0[r] + bh0));
        P[(size_t)ub_ * ROWS_ + n0 + 16 * rh + col] = __builtin_amdgcn_exp2f(SC * (acc1[r] + bh1));
    }

    __syncthreads();
    unsigned short* xtb = xT + (size_t)b * (D_ * L_) + l0;
    #pragma unroll
    for (int i = 0; i < 16; ++i) {
        const int idx = t + 256 * i;             // idx = d*16 + wq
        const int d = idx >> 4, wq = idx & 15;
        unsigned int p = *(const unsigned int*)(xtile + d * 34 + 2 * wq);
        *(unsigned int*)(xtb + (size_t)d * L_ + 2 * wq) = p;
    }
}

// ---------------------------------------------------------------------------
// K2 alpha_pv (R4-VERBATIM, proven): FUSED alpha+softmax+PV. 256 blocks x
// 512 thr (8 waves).  ~7.5 us -- at its arithmetic floor (R0/R2/R4 all
// structurally different, all neutral).
// ---------------------------------------------------------------------------
__global__ __launch_bounds__(512) void alpha_pv(const float* __restrict__ P,
                                                const float* __restrict__ WV,
                                                const void* __restrict__ x,
                                                const unsigned short* __restrict__ xT,
                                                void* __restrict__ out) {
    const int t    = threadIdx.x;
    const int w    = t >> 6;                 // 0..7
    const int lane = t & 63;
    const int row  = blockIdx.x * 8 + w;     // global row = b*L + qi
    const int b    = row >> 10;
    const int isf32 = sniff_is_f32(x);
    __shared__ unsigned short Pl[8 * PSTR];    // 16.5 KB
    __shared__ float accb[16 * 256];           // 16 KB PV partial-acc reduce

    // ---- phase 1: alpha + softmax (u-outer; lane holds keys jj*256+4*lane+c)
    const float* Pq = P + row;                              // equ: stride ROWS_ per u
    const float* kb = P + (size_t)32 * ROWS_ + (size_t)b * L_ + 4 * lane;

    float eq_l = 0.f, wu_l = 0.f;
    if (lane < U_) {
        eq_l = Pq[(size_t)lane * ROWS_];
        wu_l = WV[lane];
    }

    float alp[16];
    #pragma unroll
    for (int j = 0; j < 16; ++j) alp[j] = 0.f;

    #pragma unroll 4
    for (int u = 0; u < U_; ++u) {
        const float equ = __shfl(eq_l, u, 64);
        const float wu  = __shfl(wu_l, u, 64);
        const float* kr = kb + (size_t)u * ROWS_;
        float4 k0 = *(const float4*)(kr);
        float4 k1 = *(const float4*)(kr + 256);
        float4 k2 = *(const float4*)(kr + 512);
        float4 k3 = *(const float4*)(kr + 768);
        alp[0]  = fmaf(wu, __builtin_amdgcn_rcpf(fmaf(equ, k0.x, 1.f)), alp[0]);
        alp[1]  = fmaf(wu, __builtin_amdgcn_rcpf(fmaf(equ, k0.y, 1.f)), alp[1]);
        alp[2]  = fmaf(wu, __builtin_amdgcn_rcpf(fmaf(equ, k0.z, 1.f)), alp[2]);
        alp[3]  = fmaf(wu, __builtin_amdgcn_rcpf(fmaf(equ, k0.w, 1.f)), alp[3]);
        alp[4]  = fmaf(wu, __builtin_amdgcn_rcpf(fmaf(equ, k1.x, 1.f)), alp[4]);
        alp[5]  = fmaf(wu, __builtin_amdgcn_rcpf(fmaf(equ, k1.y, 1.f)), alp[5]);
        alp[6]  = fmaf(wu, __builtin_amdgcn_rcpf(fmaf(equ, k1.z, 1.f)), alp[6]);
        alp[7]  = fmaf(wu, __builtin_amdgcn_rcpf(fmaf(equ, k1.w, 1.f)), alp[7]);
        alp[8]  = fmaf(wu, __builtin_amdgcn_rcpf(fmaf(equ, k2.x, 1.f)), alp[8]);
        alp[9]  = fmaf(wu, __builtin_amdgcn_rcpf(fmaf(equ, k2.y, 1.f)), alp[9]);
        alp[10] = fmaf(wu, __builtin_amdgcn_rcpf(fmaf(equ, k2.z, 1.f)), alp[10]);
        alp[11] = fmaf(wu, __builtin_amdgcn_rcpf(fmaf(equ, k2.w, 1.f)), alp[11]);
        alp[12] = fmaf(wu, __builtin_amdgcn_rcpf(fmaf(equ, k3.x, 1.f)), alp[12]);
        alp[13] = fmaf(wu, __builtin_amdgcn_rcpf(fmaf(equ, k3.y, 1.f)), alp[13]);
        alp[14] = fmaf(wu, __builtin_amdgcn_rcpf(fmaf(equ, k3.z, 1.f)), alp[14]);
        alp[15] = fmaf(wu, __builtin_amdgcn_rcpf(fmaf(equ, k3.w, 1.f)), alp[15]);
    }

    float amax = alp[0];
    #pragma unroll
    for (int j = 1; j < 16; ++j) amax = fmaxf(amax, alp[j]);
    #pragma unroll
    for (int off = 32; off > 0; off >>= 1) amax = fmaxf(amax, __shfl_xor(amax, off, 64));

    const float L2E = 1.4426950408889634f;
    float s = 0.f;
    #pragma unroll
    for (int j = 0; j < 16; ++j) {
        alp[j] = __builtin_amdgcn_exp2f((alp[j] - amax) * L2E);
        s += alp[j];
    }
    #pragma unroll
    for (int off = 32; off > 0; off >>= 1) s += __shfl_xor(s, off, 64);
    const float rinv = __builtin_amdgcn_rcpf(s);

    #pragma unroll
    for (int jj = 0; jj < 4; ++jj) {
        ushort4 pk;
        pk.x = f2bf(alp[4*jj+0] * rinv);
        pk.y = f2bf(alp[4*jj+1] * rinv);
        pk.z = f2bf(alp[4*jj+2] * rinv);
        pk.w = f2bf(alp[4*jj+3] * rinv);
        *(ushort4*)(Pl + w * PSTR + jj * 256 + 4 * lane) = pk;   // key = jj*256+4*lane+c
    }
    __syncthreads();

    // ---- phase 2: PV, key-split.  wave (ds,kh): d [64ds,64ds+64) x keys [512kh,+512)
    const int ds = w & 3;
    const int kh = w >> 2;
    const int m  = lane & 15;
    const int ko = (lane >> 4) * 8 + kh * 512;
    const int d0 = ds * 64;
    const unsigned short* xbb = xT + (size_t)b * (D_ * L_) + (size_t)(d0 + m) * L_ + ko;
    const unsigned short* xb0 = xbb;
    const unsigned short* xb1 = xbb + (size_t)16 * L_;
    const unsigned short* xb2 = xbb + (size_t)32 * L_;
    const unsigned short* xb3 = xbb + (size_t)48 * L_;
    const unsigned short* pp  = Pl + (size_t)(m & 7) * PSTR + ko;  // A rows 8-15 alias 0-7

    floatx4 acc0 = {0,0,0,0}, acc1 = {0,0,0,0}, acc2 = {0,0,0,0}, acc3 = {0,0,0,0};
    short8 pa = *(const short8*)(pp);
    short8 x0 = *(const short8*)(xb0);
    short8 x1 = *(const short8*)(xb1);
    short8 x2 = *(const short8*)(xb2);
    short8 x3 = *(const short8*)(xb3);
    for (int ks = 32; ks < 512; ks += 32) {
        short8 npa = *(const short8*)(pp + ks);
        short8 nx0 = *(const short8*)(xb0 + ks);
        short8 nx1 = *(const short8*)(xb1 + ks);
        short8 nx2 = *(const short8*)(xb2 + ks);
        short8 nx3 = *(const short8*)(xb3 + ks);
        acc0 = __builtin_amdgcn_mfma_f32_16x16x32_bf16(pa, x0, acc0, 0, 0, 0);
        acc1 = __builtin_amdgcn_mfma_f32_16x16x32_bf16(pa, x1, acc1, 0, 0, 0);
        acc2 = __builtin_amdgcn_mfma_f32_16x16x32_bf16(pa, x2, acc2, 0, 0, 0);
        acc3 = __builtin_amdgcn_mfma_f32_16x16x32_bf16(pa, x3, acc3, 0, 0, 0);
        pa = npa; x0 = nx0; x1 = nx1; x2 = nx2; x3 = nx3;
    }
    acc0 = __builtin_amdgcn_mfma_f32_16x16x32_bf16(pa, x0, acc0, 0, 0, 0);
    acc1 = __builtin_amdgcn_mfma_f32_16x16x32_bf16(pa, x1, acc1, 0, 0, 0);
    acc2 = __builtin_amdgcn_mfma_f32_16x16x32_bf16(pa, x2, acc2, 0, 0, 0);
    acc3 = __builtin_amdgcn_mfma_f32_16x16x32_bf16(pa, x3, acc3, 0, 0, 0);

    // kh=1 deposits partials; kh=0 reduces and stores
    if (kh == 1) {
        *(floatx4*)(&accb[(ds * 4 + 0) * 256 + lane * 4]) = acc0;
        *(floatx4*)(&accb[(ds * 4 + 1) * 256 + lane * 4]) = acc1;
        *(floatx4*)(&accb[(ds * 4 + 2) * 256 + lane * 4]) = acc2;
        *(floatx4*)(&accb[(ds * 4 + 3) * 256 + lane * 4]) = acc3;
    }
    __syncthreads();

    if (kh == 0) {
        acc0 += *(const floatx4*)(&accb[(ds * 4 + 0) * 256 + lane * 4]);
        acc1 += *(const floatx4*)(&accb[(ds * 4 + 1) * 256 + lane * 4]);
        acc2 += *(const floatx4*)(&accb[(ds * 4 + 2) * 256 + lane * 4]);
        acc3 += *(const floatx4*)(&accb[(ds * 4 + 3) * 256 + lane * 4]);

        // C/D layout: col = lane&15 (= d offset), row = (lane>>4)*4 + reg (= q)
        const int col = lane & 15;
        const int rb  = (lane >> 4) * 4;
        const int qi0 = (blockIdx.x * 8) & (L_ - 1);   // LOCAL q index
        const size_t obase = (size_t)b * (L_ * D_) + (size_t)qi0 * D_;
        if (rb < 8) {   // lanes 0-31 hold valid q-rows 0-7
            if (isf32) {
                float* ob = (float*)out + obase;
                #pragma unroll
                for (int r = 0; r < 4; ++r) {
                    ob[(size_t)(rb + r) * D_ + d0 + col]      = acc0[r];
                    ob[(size_t)(rb + r) * D_ + d0 + 16 + col] = acc1[r];
                    ob[(size_t)(rb + r) * D_ + d0 + 32 + col] = acc2[r];
                    ob[(size_t)(rb + r) * D_ + d0 + 48 + col] = acc3[r];
                }
            } else {
                unsigned short* ob = (unsigned short*)out + obase;
                #pragma unroll
                for (int r = 0; r < 4; ++r) {
                    ob[(size_t)(rb + r) * D_ + d0 + col]      = f2bf(acc0[r]);
                    ob[(size_t)(rb + r) * D_ + d0 + 16 + col] = f2bf(acc1[r]);
                    ob[(size_t)(rb + r) * D_ + d0 + 32 + col] = f2bf(acc2[r]);
                    ob[(size_t)(rb + r) * D_ + d0 + 48 + col] = f2bf(acc3[r]);
                }
            }
        }
    }
}

extern "C" void kernel_launch(void* const* d_in, const int* in_sizes, int n_in,
                              void* d_out, int out_size, void* d_ws, size_t ws_size,
                              hipStream_t stream) {
    const void* x  = d_in[0];   // [B,L,D]  dtype sniffed at runtime (fp32 expected)
    const void* Wt = d_in[1];   // [D,U]
    const void* Wx = d_in[2];   // [U,D]
    const void* bh = d_in[3];   // [U]
    const void* Wa = d_in[4];   // [U,1]
    // d_in[5] = ba: constant pre-softmax shift -> mathematically irrelevant.

    char* ws = (char*)d_ws;
    float*          P   = (float*)(ws + OFF_P);
    unsigned short* xT  = (unsigned short*)(ws + OFF_XT);
    float*          WV  = (float*)(ws + OFF_WV);

    proj_all<<<ROWS_ / 32, 256, 0, stream>>>(x, Wt, Wx, bh, Wa, P, xT, WV);
    alpha_pv<<<ROWS_ / 8, 512, 0, stream>>>(P, WV, x, xT, d_out);
}

// Round 6
// 97.761 us; speedup vs baseline: 1.1546x; 1.0332x over previous
//
#include <hip/hip_runtime.h>
#include <cstdint>
#include <cmath>

#define B_ 2
#define L_ 1024
#define D_ 256
#define U_ 32
#define ROWS_ 2048   // B_*L_
#define WBS 280      // LDS wb row stride (halfwords): 560B, 16B-aligned
#define PSTR 1032    // LDS P row stride (halfwords): 2064B, 16B-aligned

typedef __attribute__((ext_vector_type(8))) short short8;
typedef __attribute__((ext_vector_type(4))) float floatx4;

// ---- workspace layout (bytes) ------------------------------------------------
// P holds EXP2 of the scaled logits: rows 0-31: equ = exp2(SC*(q·Wt+bh));
// rows 32-63: ekk = exp2(SC*(k·Wx)).  exp2(qu+kk) == equ*ekk (hoisted).
#define OFF_P  0u                      // [64][2048] f32 = 512 KB
#define OFF_XT (OFF_P + 524288u)       // [B][D][L] bf16 = 1 MB
#define OFF_WV (OFF_XT + 1048576u)     // [32] f32 = 128 B  (-2*Wa)

// TIME MODEL (validated R0-R5):
//   dur_us ~= 2 x 41 us poison-fills (harness reset, fixed tax)
//           + proj_all + alpha_pv.
//   R5 confirmed: vectorizing K1 staging 113 -> 101 us (predicted 100+-3).
//   Now: K1 ~11 us (1 wave/SIMD on 64 CUs -- latency-exposed), K2 ~7.5 us
//   (at floor; R0/R2/R4 all neutral).  R6 = K1 K-split to 8 waves (sole
//   change; R3's crash-round also changed K2, which R4 then proved correct).

__device__ __forceinline__ float bf2f(unsigned short u) {
    union { unsigned int i; float f; } v; v.i = ((unsigned int)u) << 16; return v.f;
}
__device__ __forceinline__ unsigned short f2bf(float f) {
    union { float f; unsigned int i; } v; v.f = f;
    unsigned int r = v.i + 0x7FFFu + ((v.i >> 16) & 1u);
    return (unsigned short)(r >> 16);
}
__device__ __forceinline__ unsigned int pack_bf(float a, float b) {
    union { float f; unsigned int i; } ua, ub; ua.f = a; ub.f = b;
    unsigned int ra = ua.i + 0x7FFFu + ((ua.i >> 16) & 1u);
    unsigned int rb = ub.i + 0x7FFFu + ((ub.i >> 16) & 1u);
    return (ra >> 16) | (rb & 0xFFFF0000u);
}

// Inline dtype sniff (per wave). Returns 1 = fp32, 0 = bf16.
__device__ __forceinline__ int sniff_is_f32(const void* x) {
    const unsigned short* xu = (const unsigned short*)x;
    float f = bf2f(xu[2 * (threadIdx.x & 63)]);
    bool plausible = (f == f) && (fabsf(f) < 1e4f) && (fabsf(f) > 1e-10f);
    unsigned long long m = __ballot(plausible);
    return (__popcll(m) >= 60) ? 0 : 1;
}

// convert 8 consecutive f32 -> short8 bf16 (RNE)
__device__ __forceinline__ short8 cvt8(const float* p) {
    float4 fa = *(const float4*)p;
    float4 fb = *(const float4*)(p + 4);
    union { short8 s; unsigned int u[4]; } r;
    r.u[0] = pack_bf(fa.x, fa.y);
    r.u[1] = pack_bf(fa.z, fa.w);
    r.u[2] = pack_bf(fb.x, fb.y);
    r.u[3] = pack_bf(fb.z, fb.w);
    return r.s;
}

// ---------------------------------------------------------------------------
// K1 proj_all (R6: K-SPLIT, sole change this round). 64 blocks x 512 thr =
// 8 waves (mt, rh, kh): mt = u-half (q units 0-31 / k units 32-63), rh =
// row-half (16 rows), kh = K-half (128 of D=256).
//   1. stage Wt^T / Wx -> LDS wb bf16; 4 float4/ushort4 loads per thread
//      per matrix (R5-proven vectorized form, now spread over 512 thr).
//   2. each wave: 4 MFMA iters (was 8) over its K-half; mt=0 waves deposit
//      x B-frags into xtile (disjoint (ks, row) cells across rh/kh/kho).
//   3. partial accs -> accb (16B-aligned), barrier, kh=0 reduces + stores
//      P = exp2(SC*logit).
//   4. coalesced uint stores of xtile -> xT[b][d][l].
// Rationale: R5 left K1 at ~11 us = 1 wave/SIMD on 64 CUs, every chain
// latency-exposed.  8 waves -> 2 waves/SIMD + all serial chains halved.
// Block 0 also precomputes WV[u] = -2*Wa[u] (f32).
// ---------------------------------------------------------------------------
__global__ __launch_bounds__(512) void proj_all(const void* __restrict__ x,  const void* __restrict__ Wt,
                         const void* __restrict__ Wx, const void* __restrict__ bh,
                         const void* __restrict__ Wa,
                         float* __restrict__ P, unsigned short* __restrict__ xT,
                         float* __restrict__ WV) {
    const int t = threadIdx.x;
    const int isf32 = sniff_is_f32(x);
    const int n0 = blockIdx.x * 32;
    const int b  = n0 >> 10;
    const int l0 = n0 & (L_ - 1);
    __shared__ unsigned short wb[64 * WBS];              // 35.0 KB
    __shared__ unsigned short xtile[D_ * 34];            // 17.0 KB
    __shared__ __align__(16) float accb[8 * 512];        // 16.0 KB partial accs

    if (blockIdx.x == 0 && t < U_) {
        float wav = isf32 ? ((const float*)Wa)[t] : bf2f(((const unsigned short*)Wa)[t]);
        WV[t] = -2.0f * wav;
    }

    // Wt staging: i = 4*(t+512j), j<4.  i 4-aligned -> u = i&31 <= 28, so
    // elements i..i+3 are u..u+3 at the SAME d.  wb[u*WBS + d] = Wt[i].
    #pragma unroll
    for (int j = 0; j < 4; ++j) {
        const int i = 4 * (t + 512 * j);
        unsigned short h0, h1, h2, h3;
        if (isf32) {
            float4 v = *(const float4*)((const float*)Wt + i);
            h0 = f2bf(v.x); h1 = f2bf(v.y); h2 = f2bf(v.z); h3 = f2bf(v.w);
        } else {
            ushort4 v = *(const ushort4*)((const unsigned short*)Wt + i);
            h0 = v.x; h1 = v.y; h2 = v.z; h3 = v.w;
        }
        const int d = i >> 5, u = i & 31;
        wb[(u + 0) * WBS + d] = h0;
        wb[(u + 1) * WBS + d] = h1;
        wb[(u + 2) * WBS + d] = h2;
        wb[(u + 3) * WBS + d] = h3;
    }
    // Wx staging: e = 4*(t+512j): elems e..e+3 share row 32+(e>>8), cols
    // (e&255)..+3 contiguous -> one 8B-aligned ushort4 LDS write.
    #pragma unroll
    for (int j = 0; j < 4; ++j) {
        const int e = 4 * (t + 512 * j);
        ushort4 o;
        if (isf32) {
            float4 v = *(const float4*)((const float*)Wx + e);
            o.x = f2bf(v.x); o.y = f2bf(v.y); o.z = f2bf(v.z); o.w = f2bf(v.w);
        } else {
            o = *(const ushort4*)((const unsigned short*)Wx + e);
        }
        *(ushort4*)(wb + (32 + (e >> 8)) * WBS + (e & 255)) = o;
    }
    __syncthreads();

    const int w    = t >> 6;
    const int lane = t & 63;
    const int mt   = w & 1;         // u-half
    const int rh   = (w >> 1) & 1;  // row-half (16 rows)
    const int kh   = w >> 2;        // K-half (128)
    const int m    = lane & 15;
    const int kho  = lane >> 4;
    const int u0   = mt * 32;
    const int row  = n0 + 16 * rh + m;
    const int kb0  = kh * 128;

    floatx4 acc0 = {0,0,0,0}, acc1 = {0,0,0,0};
    #pragma unroll
    for (int k0 = 0; k0 < 128; k0 += 32) {
        const int ks = kb0 + k0 + kho * 8;
        short8 a0 = *(const short8*)(wb + (u0 + m) * WBS + ks);
        short8 a1 = *(const short8*)(wb + (u0 + 16 + m) * WBS + ks);
        short8 b0;
        if (isf32) b0 = cvt8((const float*)x + (size_t)row * D_ + ks);
        else       b0 = *(const short8*)((const unsigned short*)x + (size_t)row * D_ + ks);
        acc0 = __builtin_amdgcn_mfma_f32_16x16x32_bf16(a0, b0, acc0, 0, 0, 0);
        acc1 = __builtin_amdgcn_mfma_f32_16x16x32_bf16(a1, b0, acc1, 0, 0, 0);
        if (mt == 0) {    // waves (rh, kh) x lanes (kho, m) cover (row, ks) disjointly
            union { short8 s; unsigned short h[8]; } uu; uu.s = b0;
            #pragma unroll
            for (int jj = 0; jj < 8; ++jj)
                xtile[(ks + jj) * 34 + 16 * rh + m] = uu.h[jj];
        }
    }

    // partial-acc deposit + reduce across kh pairs (w and w+4)
    *(floatx4*)(&accb[w * 512 + lane * 4])       = acc0;
    *(floatx4*)(&accb[w * 512 + 256 + lane * 4]) = acc1;
    __syncthreads();

    if (kh == 0) {
        acc0 += *(const floatx4*)(&accb[(w + 4) * 512 + lane * 4]);
        acc1 += *(const floatx4*)(&accb[(w + 4) * 512 + 256 + lane * 4]);

        const float SC = 2.0f * 1.4426950408889634f;   // 2*log2(e)
        const int col = lane & 15;
        const int rb  = (lane >> 4) * 4;
        #pragma unroll
        for (int r = 0; r < 4; ++r) {
            const int ua = u0 + rb + r, ub_ = u0 + 16 + rb + r;
            float bh0 = 0.f, bh1 = 0.f;
            if (mt == 0) {
                bh0 = isf32 ? ((const float*)bh)[rb + r]      : bf2f(((const unsigned short*)bh)[rb + r]);
                bh1 = isf32 ? ((const float*)bh)[16 + rb + r] : bf2f(((const unsigned short*)bh)[16 + rb + r]);
            }
            P[(size_t)ua  * ROWS_ + n0 + 16 * rh + col] = __builtin_amdgcn_exp2f(SC * (acc0[r] + bh0));
            P[(size_t)ub_ * ROWS_ + n0 + 16 * rh + col] = __builtin_amdgcn_exp2f(SC * (acc1[r] + bh1));
        }
    }

    // xtile complete since the accb barrier; coalesced bf16 transpose store
    unsigned short* xtb = xT + (size_t)b * (D_ * L_) + l0;
    #pragma unroll
    for (int i = 0; i < 8; ++i) {
        const int idx = t + 512 * i;             // idx = d*16 + wq
        const int d = idx >> 4, wq = idx & 15;
        unsigned int p = *(const unsigned int*)(xtile + d * 34 + 2 * wq);
        *(unsigned int*)(xtb + (size_t)d * L_ + 2 * wq) = p;
    }
}

// ---------------------------------------------------------------------------
// K2 alpha_pv (R4-VERBATIM, proven 2x): FUSED alpha+softmax+PV. 256 blocks x
// 512 thr (8 waves).  ~7.5 us -- at its arithmetic floor (R0/R2/R4 all
// structurally different, all neutral).
// ---------------------------------------------------------------------------
__global__ __launch_bounds__(512) void alpha_pv(const float* __restrict__ P,
                                                const float* __restrict__ WV,
                                                const void* __restrict__ x,
                                                const unsigned short* __restrict__ xT,
                                                void* __restrict__ out) {
    const int t    = threadIdx.x;
    const int w    = t >> 6;                 // 0..7
    const int lane = t & 63;
    const int row  = blockIdx.x * 8 + w;     // global row = b*L + qi
    const int b    = row >> 10;
    const int isf32 = sniff_is_f32(x);
    __shared__ unsigned short Pl[8 * PSTR];            // 16.5 KB
    __shared__ __align__(16) float accb[16 * 256];     // 16 KB PV partial-acc reduce

    // ---- phase 1: alpha + softmax (u-outer; lane holds keys jj*256+4*lane+c)
    const float* Pq = P + row;                              // equ: stride ROWS_ per u
    const float* kb = P + (size_t)32 * ROWS_ + (size_t)b * L_ + 4 * lane;

    float eq_l = 0.f, wu_l = 0.f;
    if (lane < U_) {
        eq_l = Pq[(size_t)lane * ROWS_];
        wu_l = WV[lane];
    }

    float alp[16];
    #pragma unroll
    for (int j = 0; j < 16; ++j) alp[j] = 0.f;

    #pragma unroll 4
    for (int u = 0; u < U_; ++u) {
        const float equ = __shfl(eq_l, u, 64);
        const float wu  = __shfl(wu_l, u, 64);
        const float* kr = kb + (size_t)u * ROWS_;
        float4 k0 = *(const float4*)(kr);
        float4 k1 = *(const float4*)(kr + 256);
        float4 k2 = *(const float4*)(kr + 512);
        float4 k3 = *(const float4*)(kr + 768);
        alp[0]  = fmaf(wu, __builtin_amdgcn_rcpf(fmaf(equ, k0.x, 1.f)), alp[0]);
        alp[1]  = fmaf(wu, __builtin_amdgcn_rcpf(fmaf(equ, k0.y, 1.f)), alp[1]);
        alp[2]  = fmaf(wu, __builtin_amdgcn_rcpf(fmaf(equ, k0.z, 1.f)), alp[2]);
        alp[3]  = fmaf(wu, __builtin_amdgcn_rcpf(fmaf(equ, k0.w, 1.f)), alp[3]);
        alp[4]  = fmaf(wu, __builtin_amdgcn_rcpf(fmaf(equ, k1.x, 1.f)), alp[4]);
        alp[5]  = fmaf(wu, __builtin_amdgcn_rcpf(fmaf(equ, k1.y, 1.f)), alp[5]);
        alp[6]  = fmaf(wu, __builtin_amdgcn_rcpf(fmaf(equ, k1.z, 1.f)), alp[6]);
        alp[7]  = fmaf(wu, __builtin_amdgcn_rcpf(fmaf(equ, k1.w, 1.f)), alp[7]);
        alp[8]  = fmaf(wu, __builtin_amdgcn_rcpf(fmaf(equ, k2.x, 1.f)), alp[8]);
        alp[9]  = fmaf(wu, __builtin_amdgcn_rcpf(fmaf(equ, k2.y, 1.f)), alp[9]);
        alp[10] = fmaf(wu, __builtin_amdgcn_rcpf(fmaf(equ, k2.z, 1.f)), alp[10]);
        alp[11] = fmaf(wu, __builtin_amdgcn_rcpf(fmaf(equ, k2.w, 1.f)), alp[11]);
        alp[12] = fmaf(wu, __builtin_amdgcn_rcpf(fmaf(equ, k3.x, 1.f)), alp[12]);
        alp[13] = fmaf(wu, __builtin_amdgcn_rcpf(fmaf(equ, k3.y, 1.f)), alp[13]);
        alp[14] = fmaf(wu, __builtin_amdgcn_rcpf(fmaf(equ, k3.z, 1.f)), alp[14]);
        alp[15] = fmaf(wu, __builtin_amdgcn_rcpf(fmaf(equ, k3.w, 1.f)), alp[15]);
    }

    float amax = alp[0];
    #pragma unroll
    for (int j = 1; j < 16; ++j) amax = fmaxf(amax, alp[j]);
    #pragma unroll
    for (int off = 32; off > 0; off >>= 1) amax = fmaxf(amax, __shfl_xor(amax, off, 64));

    const float L2E = 1.4426950408889634f;
    float s = 0.f;
    #pragma unroll
    for (int j = 0; j < 16; ++j) {
        alp[j] = __builtin_amdgcn_exp2f((alp[j] - amax) * L2E);
        s += alp[j];
    }
    #pragma unroll
    for (int off = 32; off > 0; off >>= 1) s += __shfl_xor(s, off, 64);
    const float rinv = __builtin_amdgcn_rcpf(s);

    #pragma unroll
    for (int jj = 0; jj < 4; ++jj) {
        ushort4 pk;
        pk.x = f2bf(alp[4*jj+0] * rinv);
        pk.y = f2bf(alp[4*jj+1] * rinv);
        pk.z = f2bf(alp[4*jj+2] * rinv);
        pk.w = f2bf(alp[4*jj+3] * rinv);
        *(ushort4*)(Pl + w * PSTR + jj * 256 + 4 * lane) = pk;   // key = jj*256+4*lane+c
    }
    __syncthreads();

    // ---- phase 2: PV, key-split.  wave (ds,kh): d [64ds,64ds+64) x keys [512kh,+512)
    const int ds = w & 3;
    const int kh = w >> 2;
    const int m  = lane & 15;
    const int ko = (lane >> 4) * 8 + kh * 512;
    const int d0 = ds * 64;
    const unsigned short* xbb = xT + (size_t)b * (D_ * L_) + (size_t)(d0 + m) * L_ + ko;
    const unsigned short* xb0 = xbb;
    const unsigned short* xb1 = xbb + (size_t)16 * L_;
    const unsigned short* xb2 = xbb + (size_t)32 * L_;
    const unsigned short* xb3 = xbb + (size_t)48 * L_;
    const unsigned short* pp  = Pl + (size_t)(m & 7) * PSTR + ko;  // A rows 8-15 alias 0-7

    floatx4 acc0 = {0,0,0,0}, acc1 = {0,0,0,0}, acc2 = {0,0,0,0}, acc3 = {0,0,0,0};
    short8 pa = *(const short8*)(pp);
    short8 x0 = *(const short8*)(xb0);
    short8 x1 = *(const short8*)(xb1);
    short8 x2 = *(const short8*)(xb2);
    short8 x3 = *(const short8*)(xb3);
    for (int ks = 32; ks < 512; ks += 32) {
        short8 npa = *(const short8*)(pp + ks);
        short8 nx0 = *(const short8*)(xb0 + ks);
        short8 nx1 = *(const short8*)(xb1 + ks);
        short8 nx2 = *(const short8*)(xb2 + ks);
        short8 nx3 = *(const short8*)(xb3 + ks);
        acc0 = __builtin_amdgcn_mfma_f32_16x16x32_bf16(pa, x0, acc0, 0, 0, 0);
        acc1 = __builtin_amdgcn_mfma_f32_16x16x32_bf16(pa, x1, acc1, 0, 0, 0);
        acc2 = __builtin_amdgcn_mfma_f32_16x16x32_bf16(pa, x2, acc2, 0, 0, 0);
        acc3 = __builtin_amdgcn_mfma_f32_16x16x32_bf16(pa, x3, acc3, 0, 0, 0);
        pa = npa; x0 = nx0; x1 = nx1; x2 = nx2; x3 = nx3;
    }
    acc0 = __builtin_amdgcn_mfma_f32_16x16x32_bf16(pa, x0, acc0, 0, 0, 0);
    acc1 = __builtin_amdgcn_mfma_f32_16x16x32_bf16(pa, x1, acc1, 0, 0, 0);
    acc2 = __builtin_amdgcn_mfma_f32_16x16x32_bf16(pa, x2, acc2, 0, 0, 0);
    acc3 = __builtin_amdgcn_mfma_f32_16x16x32_bf16(pa, x3, acc3, 0, 0, 0);

    // kh=1 deposits partials; kh=0 reduces and stores
    if (kh == 1) {
        *(floatx4*)(&accb[(ds * 4 + 0) * 256 + lane * 4]) = acc0;
        *(floatx4*)(&accb[(ds * 4 + 1) * 256 + lane * 4]) = acc1;
        *(floatx4*)(&accb[(ds * 4 + 2) * 256 + lane * 4]) = acc2;
        *(floatx4*)(&accb[(ds * 4 + 3) * 256 + lane * 4]) = acc3;
    }
    __syncthreads();

    if (kh == 0) {
        acc0 += *(const floatx4*)(&accb[(ds * 4 + 0) * 256 + lane * 4]);
        acc1 += *(const floatx4*)(&accb[(ds * 4 + 1) * 256 + lane * 4]);
        acc2 += *(const floatx4*)(&accb[(ds * 4 + 2) * 256 + lane * 4]);
        acc3 += *(const floatx4*)(&accb[(ds * 4 + 3) * 256 + lane * 4]);

        // C/D layout: col = lane&15 (= d offset), row = (lane>>4)*4 + reg (= q)
        const int col = lane & 15;
        const int rb  = (lane >> 4) * 4;
        const int qi0 = (blockIdx.x * 8) & (L_ - 1);   // LOCAL q index
        const size_t obase = (size_t)b * (L_ * D_) + (size_t)qi0 * D_;
        if (rb < 8) {   // lanes 0-31 hold valid q-rows 0-7
            if (isf32) {
                float* ob = (float*)out + obase;
                #pragma unroll
                for (int r = 0; r < 4; ++r) {
                    ob[(size_t)(rb + r) * D_ + d0 + col]      = acc0[r];
                    ob[(size_t)(rb + r) * D_ + d0 + 16 + col] = acc1[r];
                    ob[(size_t)(rb + r) * D_ + d0 + 32 + col] = acc2[r];
                    ob[(size_t)(rb + r) * D_ + d0 + 48 + col] = acc3[r];
                }
            } else {
                unsigned short* ob = (unsigned short*)out + obase;
                #pragma unroll
                for (int r = 0; r < 4; ++r) {
                    ob[(size_t)(rb + r) * D_ + d0 + col]      = f2bf(acc0[r]);
                    ob[(size_t)(rb + r) * D_ + d0 + 16 + col] = f2bf(acc1[r]);
                    ob[(size_t)(rb + r) * D_ + d0 + 32 + col] = f2bf(acc2[r]);
                    ob[(size_t)(rb + r) * D_ + d0 + 48 + col] = f2bf(acc3[r]);
                }
            }
        }
    }
}

extern "C" void kernel_launch(void* const* d_in, const int* in_sizes, int n_in,
                              void* d_out, int out_size, void* d_ws, size_t ws_size,
                              hipStream_t stream) {
    const void* x  = d_in[0];   // [B,L,D]  dtype sniffed at runtime (fp32 expected)
    const void* Wt = d_in[1];   // [D,U]
    const void* Wx = d_in[2];   // [U,D]
    const void* bh = d_in[3];   // [U]
    const void* Wa = d_in[4];   // [U,1]
    // d_in[5] = ba: constant pre-softmax shift -> mathematically irrelevant.

    char* ws = (char*)d_ws;
    float*          P   = (float*)(ws + OFF_P);
    unsigned short* xT  = (unsigned short*)(ws + OFF_XT);
    float*          WV  = (float*)(ws + OFF_WV);

    proj_all<<<ROWS_ / 32, 512, 0, stream>>>(x, Wt, Wx, bh, Wa, P, xT, WV);
    alpha_pv<<<ROWS_ / 8, 512, 0, stream>>>(P, WV, x, xT, d_out);
}